// Round 2
// baseline (191.569 us; speedup 1.0000x reference)
//
#include <hip/hip_runtime.h>

#define N_NODES 4096
#define EDGES   16384
#define PHI     64
#define EPS_F   1e-8f
#define BETA_F  0.5f

__device__ __forceinline__ float wave_sum(float v) {
#pragma unroll
    for (int off = 32; off > 0; off >>= 1) v += __shfl_xor(v, off, 64);
    return v;
}

__device__ __forceinline__ unsigned int pack_bf16(float f) {
    unsigned int u = __float_as_uint(f);
    u += 0x7fffu + ((u >> 16) & 1u);   // round-to-nearest-even
    return u >> 16;
}

// k0: f_mean = 0.5*(f0+f1), wsq = f_mean^2
__global__ void k_prep(const float* __restrict__ f0, const float* __restrict__ f1,
                       float* __restrict__ fm, float* __restrict__ wsq) {
    int i = blockIdx.x * blockDim.x + threadIdx.x;
    if (i < N_NODES) {
        float m = 0.5f * (f0[i] + f1[i]);
        fm[i]  = m;
        wsq[i] = m * m;
    }
}

// k1 fast: per row v: B[v,:] = bf16(A[v,:]*fm), dnorm[v] = ||A[v,:]*fm + eps||
__global__ void __launch_bounds__(256) k_rows_fast(const float* __restrict__ A,
                                                   const float* __restrict__ fm,
                                                   unsigned short* __restrict__ B,
                                                   float* __restrict__ dnorm) {
    int row = blockIdx.x;
    const float4* a4  = (const float4*)(A + (size_t)row * N_NODES);
    const float4* fm4 = (const float4*)fm;
    uint2* b2 = (uint2*)(B + (size_t)row * N_NODES);
    int t = threadIdx.x;
    float acc = 0.f;
#pragma unroll
    for (int i = 0; i < 4; ++i) {
        int idx = i * 256 + t;
        float4 a = a4[idx];
        float4 f = fm4[idx];
        float b0 = a.x * f.x, b1 = a.y * f.y, b2v = a.z * f.z, b3 = a.w * f.w;
        float e0 = b0 + EPS_F, e1 = b1 + EPS_F, e2 = b2v + EPS_F, e3 = b3 + EPS_F;
        acc += e0 * e0 + e1 * e1 + e2 * e2 + e3 * e3;
        uint2 p;
        p.x = (pack_bf16(b1) << 16) | pack_bf16(b0);
        p.y = (pack_bf16(b3) << 16) | pack_bf16(b2v);
        b2[idx] = p;
    }
    acc = wave_sum(acc);
    __shared__ float red[4];
    if ((t & 63) == 0) red[t >> 6] = acc;
    __syncthreads();
    if (t == 0) dnorm[row] = sqrtf(red[0] + red[1] + red[2] + red[3]);
}

// k1 slow: dnorm only
__global__ void __launch_bounds__(256) k_rows_slow(const float* __restrict__ A,
                                                   const float* __restrict__ fm,
                                                   float* __restrict__ dnorm) {
    int row = blockIdx.x;
    const float4* a4  = (const float4*)(A + (size_t)row * N_NODES);
    const float4* fm4 = (const float4*)fm;
    int t = threadIdx.x;
    float acc = 0.f;
#pragma unroll
    for (int i = 0; i < 4; ++i) {
        int idx = i * 256 + t;
        float4 a = a4[idx];
        float4 f = fm4[idx];
        float e0 = a.x * f.x + EPS_F, e1 = a.y * f.y + EPS_F;
        float e2 = a.z * f.z + EPS_F, e3 = a.w * f.w + EPS_F;
        acc += e0 * e0 + e1 * e1 + e2 * e2 + e3 * e3;
    }
    acc = wave_sum(acc);
    __shared__ float red[4];
    if ((t & 63) == 0) red[t >> 6] = acc;
    __syncthreads();
    if (t == 0) dnorm[row] = sqrtf(red[0] + red[1] + red[2] + red[3]);
}

// Shared epilogue: given x = out_n, run both MLPs wave-parallel (lane = hidden idx)
__device__ __forceinline__ void mlp_epilogue(float x, int lid, int e, int lane,
                                             const float* __restrict__ p1w1, const float* __restrict__ p1b1,
                                             const float* __restrict__ p1w2, const float* __restrict__ p1b2,
                                             const float* __restrict__ p2w1, const float* __restrict__ p2b1,
                                             const float* __restrict__ p2w2, const float* __restrict__ p2b2,
                                             float* __restrict__ out) {
    int wi = lid * PHI + lane;
    float h1 = fmaxf(fmaf(x, p1w1[wi], p1b1[wi]), 0.f);
    float y1 = wave_sum(h1 * p1w2[wi]) + p1b2[lid];
    float sl1 = BETA_F * y1;   // LM = 1.0
    float h2 = fmaxf(fmaf(sl1, p2w1[wi], p2b1[wi]), 0.f);
    float y2 = wave_sum(h2 * p2w2[wi]) + p2b2[lid];
    if (lane == 0) out[lid * EDGES + e] = y2;
}

// k2 fast: one wave per edge; bf16 row dot + epilogue
__global__ void __launch_bounds__(256) k_edges_fast(
        const unsigned short* __restrict__ B, const float* __restrict__ dnorm,
        const int* __restrict__ src0, const int* __restrict__ dst0,
        const int* __restrict__ src1, const int* __restrict__ dst1,
        const float* __restrict__ p1w1, const float* __restrict__ p1b1,
        const float* __restrict__ p1w2, const float* __restrict__ p1b2,
        const float* __restrict__ p2w1, const float* __restrict__ p2b1,
        const float* __restrict__ p2w2, const float* __restrict__ p2b2,
        float* __restrict__ out) {
    int gw   = (int)((blockIdx.x * blockDim.x + threadIdx.x) >> 6);
    int lane = threadIdx.x & 63;
    int lid  = gw >> 14;            // 32768 waves: 0..16383 layer0, rest layer1
    int e    = gw & (EDGES - 1);
    int s = lid ? src1[e] : src0[e];
    int d = lid ? dst1[e] : dst0[e];
    const uint4* rs = (const uint4*)(B + (size_t)s * N_NODES);
    const uint4* rd = (const uint4*)(B + (size_t)d * N_NODES);
    float acc = 0.f;
#pragma unroll
    for (int i = 0; i < 8; ++i) {
        uint4 us = rs[i * 64 + lane];
        uint4 ud = rd[i * 64 + lane];
#define ACC_U(U, V)                                                    \
        {                                                              \
            float sl = __uint_as_float((U) << 16);                     \
            float sh = __uint_as_float((U) & 0xffff0000u);             \
            float dl = __uint_as_float((V) << 16);                     \
            float dh = __uint_as_float((V) & 0xffff0000u);             \
            acc = fmaf(sl, dl, acc);                                   \
            acc = fmaf(sh, dh, acc);                                   \
        }
        ACC_U(us.x, ud.x); ACC_U(us.y, ud.y); ACC_U(us.z, ud.z); ACC_U(us.w, ud.w);
#undef ACC_U
    }
    acc = wave_sum(acc);
    float x = acc / (dnorm[s] * dnorm[d]);
    mlp_epilogue(x, lid, e, lane, p1w1, p1b1, p1w2, p1b2, p2w1, p2b1, p2w2, p2b2, out);
}

// k2 slow: fp32 rows of A, weight w = fm^2 staged in LDS
__global__ void __launch_bounds__(256) k_edges_slow(
        const float* __restrict__ A, const float* __restrict__ wsq,
        const float* __restrict__ dnorm,
        const int* __restrict__ src0, const int* __restrict__ dst0,
        const int* __restrict__ src1, const int* __restrict__ dst1,
        const float* __restrict__ p1w1, const float* __restrict__ p1b1,
        const float* __restrict__ p1w2, const float* __restrict__ p1b2,
        const float* __restrict__ p2w1, const float* __restrict__ p2b1,
        const float* __restrict__ p2w2, const float* __restrict__ p2b2,
        float* __restrict__ out) {
    __shared__ float wl[N_NODES];
    int t = threadIdx.x;
    const float4* w4 = (const float4*)wsq;
    float4* wl4 = (float4*)wl;
    for (int i = t; i < N_NODES / 4; i += 256) wl4[i] = w4[i];
    __syncthreads();

    int gw   = (int)((blockIdx.x * blockDim.x + t) >> 6);
    int lane = t & 63;
    int lid  = gw >> 14;
    int e    = gw & (EDGES - 1);
    int s = lid ? src1[e] : src0[e];
    int d = lid ? dst1[e] : dst0[e];
    const float4* rs = (const float4*)(A + (size_t)s * N_NODES);
    const float4* rd = (const float4*)(A + (size_t)d * N_NODES);
    float acc = 0.f;
#pragma unroll
    for (int i = 0; i < 16; ++i) {
        int idx = i * 64 + lane;
        float4 a = rs[idx];
        float4 b = rd[idx];
        float4 w = wl4[idx];
        acc = fmaf(a.x * b.x, w.x, acc);
        acc = fmaf(a.y * b.y, w.y, acc);
        acc = fmaf(a.z * b.z, w.z, acc);
        acc = fmaf(a.w * b.w, w.w, acc);
    }
    acc = wave_sum(acc);
    float x = acc / (dnorm[s] * dnorm[d]);
    mlp_epilogue(x, lid, e, lane, p1w1, p1b1, p1w2, p1b2, p2w1, p2b1, p2w2, p2b2, out);
}

extern "C" void kernel_launch(void* const* d_in, const int* in_sizes, int n_in,
                              void* d_out, int out_size, void* d_ws, size_t ws_size,
                              hipStream_t stream) {
    const float* A    = (const float*)d_in[0];
    const int*   src0 = (const int*)d_in[1];
    const int*   dst0 = (const int*)d_in[2];
    const int*   src1 = (const int*)d_in[3];
    const int*   dst1 = (const int*)d_in[4];
    const float* f0   = (const float*)d_in[5];
    const float* f1   = (const float*)d_in[6];
    const float* p1w1 = (const float*)d_in[7];
    const float* p1b1 = (const float*)d_in[8];
    const float* p1w2 = (const float*)d_in[9];
    const float* p1b2 = (const float*)d_in[10];
    const float* p2w1 = (const float*)d_in[11];
    const float* p2b1 = (const float*)d_in[12];
    const float* p2w2 = (const float*)d_in[13];
    const float* p2b2 = (const float*)d_in[14];
    float* out = (float*)d_out;

    float* ws   = (float*)d_ws;
    float* fm   = ws;
    float* wsq  = ws + N_NODES;
    float* dn   = ws + 2 * N_NODES;
    unsigned short* B = (unsigned short*)(ws + 3 * N_NODES);
    size_t need = 3ull * N_NODES * 4 + (size_t)N_NODES * N_NODES * 2;
    bool fast = (ws_size >= need);

    k_prep<<<N_NODES / 256, 256, 0, stream>>>(f0, f1, fm, wsq);
    if (fast) {
        k_rows_fast<<<N_NODES, 256, 0, stream>>>(A, fm, B, dn);
        k_edges_fast<<<(2 * EDGES * 64) / 256, 256, 0, stream>>>(
            B, dn, src0, dst0, src1, dst1,
            p1w1, p1b1, p1w2, p1b2, p2w1, p2b1, p2w2, p2b2, out);
    } else {
        k_rows_slow<<<N_NODES, 256, 0, stream>>>(A, fm, dn);
        k_edges_slow<<<(2 * EDGES * 64) / 256, 256, 0, stream>>>(
            A, wsq, dn, src0, dst0, src1, dst1,
            p1w1, p1b1, p1w2, p1b2, p2w1, p2b1, p2w2, p2b2, out);
    }
}

// Round 3
// 172.928 us; speedup vs baseline: 1.1078x; 1.1078x over previous
//
#include <hip/hip_runtime.h>

#define N_NODES 4096
#define EDGES   16384
#define PHI     64
#define EPS_F   1e-8f
#define BETA_F  0.5f
#define NCHUNK  8
#define WCHUNK  512   // 512 bf16 cols = 1 KB = 64 lanes x uint4

__device__ __forceinline__ float wave_sum(float v) {
#pragma unroll
    for (int off = 32; off > 0; off >>= 1) v += __shfl_xor(v, off, 64);
    return v;
}

__device__ __forceinline__ unsigned int pack_bf16(float f) {
    unsigned int u = __float_as_uint(f);
    u += 0x7fffu + ((u >> 16) & 1u);   // round-to-nearest-even
    return u >> 16;
}

// k0: f_mean = 0.5*(f0+f1), wsq = f_mean^2
__global__ void k_prep(const float* __restrict__ f0, const float* __restrict__ f1,
                       float* __restrict__ fm, float* __restrict__ wsq) {
    int i = blockIdx.x * blockDim.x + threadIdx.x;
    if (i < N_NODES) {
        float m = 0.5f * (f0[i] + f1[i]);
        fm[i]  = m;
        wsq[i] = m * m;
    }
}

// k1: per row v: B[v,:] = bf16(A[v,:]*fm), dnorm[v] = ||A[v,:]*fm + eps||
__global__ void __launch_bounds__(256) k_rows_fast(const float* __restrict__ A,
                                                   const float* __restrict__ fm,
                                                   unsigned short* __restrict__ B,
                                                   float* __restrict__ dnorm) {
    int row = blockIdx.x;
    const float4* a4  = (const float4*)(A + (size_t)row * N_NODES);
    const float4* fm4 = (const float4*)fm;
    uint2* b2 = (uint2*)(B + (size_t)row * N_NODES);
    int t = threadIdx.x;
    float acc = 0.f;
#pragma unroll
    for (int i = 0; i < 4; ++i) {
        int idx = i * 256 + t;
        float4 a = a4[idx];
        float4 f = fm4[idx];
        float b0 = a.x * f.x, b1 = a.y * f.y, b2v = a.z * f.z, b3 = a.w * f.w;
        float e0 = b0 + EPS_F, e1 = b1 + EPS_F, e2 = b2v + EPS_F, e3 = b3 + EPS_F;
        acc += e0 * e0 + e1 * e1 + e2 * e2 + e3 * e3;
        uint2 p;
        p.x = (pack_bf16(b1) << 16) | pack_bf16(b0);
        p.y = (pack_bf16(b3) << 16) | pack_bf16(b2v);
        b2[idx] = p;
    }
    acc = wave_sum(acc);
    __shared__ float red[4];
    if ((t & 63) == 0) red[t >> 6] = acc;
    __syncthreads();
    if (t == 0) dnorm[row] = sqrtf(red[0] + red[1] + red[2] + red[3]);
}

// k1 slow: dnorm only
__global__ void __launch_bounds__(256) k_rows_slow(const float* __restrict__ A,
                                                   const float* __restrict__ fm,
                                                   float* __restrict__ dnorm) {
    int row = blockIdx.x;
    const float4* a4  = (const float4*)(A + (size_t)row * N_NODES);
    const float4* fm4 = (const float4*)fm;
    int t = threadIdx.x;
    float acc = 0.f;
#pragma unroll
    for (int i = 0; i < 4; ++i) {
        int idx = i * 256 + t;
        float4 a = a4[idx];
        float4 f = fm4[idx];
        float e0 = a.x * f.x + EPS_F, e1 = a.y * f.y + EPS_F;
        float e2 = a.z * f.z + EPS_F, e3 = a.w * f.w + EPS_F;
        acc += e0 * e0 + e1 * e1 + e2 * e2 + e3 * e3;
    }
    acc = wave_sum(acc);
    __shared__ float red[4];
    if ((t & 63) == 0) red[t >> 6] = acc;
    __syncthreads();
    if (t == 0) dnorm[row] = sqrtf(red[0] + red[1] + red[2] + red[3]);
}

// Shared epilogue: given x = out_n, run both MLPs wave-parallel (lane = hidden idx)
__device__ __forceinline__ void mlp_epilogue(float x, int lid, int e, int lane,
                                             const float* __restrict__ p1w1, const float* __restrict__ p1b1,
                                             const float* __restrict__ p1w2, const float* __restrict__ p1b2,
                                             const float* __restrict__ p2w1, const float* __restrict__ p2b1,
                                             const float* __restrict__ p2w2, const float* __restrict__ p2b2,
                                             float* __restrict__ out) {
    int wi = lid * PHI + lane;
    float h1 = fmaxf(fmaf(x, p1w1[wi], p1b1[wi]), 0.f);
    float y1 = wave_sum(h1 * p1w2[wi]) + p1b2[lid];
    float sl1 = BETA_F * y1;   // LM = 1.0
    float h2 = fmaxf(fmaf(sl1, p2w1[wi], p2b1[wi]), 0.f);
    float y2 = wave_sum(h2 * p2w2[wi]) + p2b2[lid];
    if (lane == 0) out[lid * EDGES + e] = y2;
}

// k2 chunked: chunk = blockIdx & 7 -> one 4MB column-slab per XCD (L2-resident).
// 16384 blocks x 4 waves; each wave does 4 edges over its chunk's 512 columns.
__global__ void __launch_bounds__(256) k_edges_chunk(
        const unsigned short* __restrict__ B,
        const int* __restrict__ src0, const int* __restrict__ dst0,
        const int* __restrict__ src1, const int* __restrict__ dst1,
        float* __restrict__ P) {
    int blk   = blockIdx.x;
    int chunk = blk & (NCHUNK - 1);
    int slot  = blk >> 3;
    int wave  = threadIdx.x >> 6;
    int lane  = threadIdx.x & 63;
    int ge0   = slot * 16 + wave * 4;          // 4 edges per wave
    const unsigned short* Bc = B + (size_t)chunk * WCHUNK;
#pragma unroll
    for (int k = 0; k < 4; ++k) {
        int ge  = ge0 + k;                     // [0, 32768)
        int lid = ge >> 14;
        int e   = ge & (EDGES - 1);
        int s = lid ? src1[e] : src0[e];
        int d = lid ? dst1[e] : dst0[e];
        uint4 us = *((const uint4*)(Bc + (size_t)s * N_NODES) + lane);
        uint4 ud = *((const uint4*)(Bc + (size_t)d * N_NODES) + lane);
        float acc = 0.f;
#define ACC_U(U, V)                                                    \
        {                                                              \
            float sl = __uint_as_float((U) << 16);                     \
            float sh = __uint_as_float((U) & 0xffff0000u);             \
            float dl = __uint_as_float((V) << 16);                     \
            float dh = __uint_as_float((V) & 0xffff0000u);             \
            acc = fmaf(sl, dl, acc);                                   \
            acc = fmaf(sh, dh, acc);                                   \
        }
        ACC_U(us.x, ud.x); ACC_U(us.y, ud.y); ACC_U(us.z, ud.z); ACC_U(us.w, ud.w);
#undef ACC_U
        acc = wave_sum(acc);
        if (lane == 0) P[(size_t)ge * NCHUNK + chunk] = acc;
    }
}

// k3: reduce 8 partials per edge, normalize, run both MLPs
__global__ void __launch_bounds__(256) k_finish(
        const float* __restrict__ P, const float* __restrict__ dnorm,
        const int* __restrict__ src0, const int* __restrict__ dst0,
        const int* __restrict__ src1, const int* __restrict__ dst1,
        const float* __restrict__ p1w1, const float* __restrict__ p1b1,
        const float* __restrict__ p1w2, const float* __restrict__ p1b2,
        const float* __restrict__ p2w1, const float* __restrict__ p2b1,
        const float* __restrict__ p2w2, const float* __restrict__ p2b2,
        float* __restrict__ out) {
    int gw   = (int)((blockIdx.x * blockDim.x + threadIdx.x) >> 6);   // [0, 32768)
    int lane = threadIdx.x & 63;
    int lid  = gw >> 14;
    int e    = gw & (EDGES - 1);
    int s = lid ? src1[e] : src0[e];
    int d = lid ? dst1[e] : dst0[e];
    float acc = 0.f;
#pragma unroll
    for (int c = 0; c < NCHUNK; ++c) acc += P[(size_t)gw * NCHUNK + c];
    float x = acc / (dnorm[s] * dnorm[d]);
    mlp_epilogue(x, lid, e, lane, p1w1, p1b1, p1w2, p1b2, p2w1, p2b1, p2w2, p2b2, out);
}

// Round-2 fallback: one wave per edge over full rows (monolithic)
__global__ void __launch_bounds__(256) k_edges_fast(
        const unsigned short* __restrict__ B, const float* __restrict__ dnorm,
        const int* __restrict__ src0, const int* __restrict__ dst0,
        const int* __restrict__ src1, const int* __restrict__ dst1,
        const float* __restrict__ p1w1, const float* __restrict__ p1b1,
        const float* __restrict__ p1w2, const float* __restrict__ p1b2,
        const float* __restrict__ p2w1, const float* __restrict__ p2b1,
        const float* __restrict__ p2w2, const float* __restrict__ p2b2,
        float* __restrict__ out) {
    int gw   = (int)((blockIdx.x * blockDim.x + threadIdx.x) >> 6);
    int lane = threadIdx.x & 63;
    int lid  = gw >> 14;
    int e    = gw & (EDGES - 1);
    int s = lid ? src1[e] : src0[e];
    int d = lid ? dst1[e] : dst0[e];
    const uint4* rs = (const uint4*)(B + (size_t)s * N_NODES);
    const uint4* rd = (const uint4*)(B + (size_t)d * N_NODES);
    float acc = 0.f;
#pragma unroll
    for (int i = 0; i < 8; ++i) {
        uint4 us = rs[i * 64 + lane];
        uint4 ud = rd[i * 64 + lane];
#define ACC_U(U, V)                                                    \
        {                                                              \
            float sl = __uint_as_float((U) << 16);                     \
            float sh = __uint_as_float((U) & 0xffff0000u);             \
            float dl = __uint_as_float((V) << 16);                     \
            float dh = __uint_as_float((V) & 0xffff0000u);             \
            acc = fmaf(sl, dl, acc);                                   \
            acc = fmaf(sh, dh, acc);                                   \
        }
        ACC_U(us.x, ud.x); ACC_U(us.y, ud.y); ACC_U(us.z, ud.z); ACC_U(us.w, ud.w);
#undef ACC_U
    }
    acc = wave_sum(acc);
    float x = acc / (dnorm[s] * dnorm[d]);
    mlp_epilogue(x, lid, e, lane, p1w1, p1b1, p1w2, p1b2, p2w1, p2b1, p2w2, p2b2, out);
}

// Slow fallback: fp32 rows of A, weight w = fm^2 staged in LDS
__global__ void __launch_bounds__(256) k_edges_slow(
        const float* __restrict__ A, const float* __restrict__ wsq,
        const float* __restrict__ dnorm,
        const int* __restrict__ src0, const int* __restrict__ dst0,
        const int* __restrict__ src1, const int* __restrict__ dst1,
        const float* __restrict__ p1w1, const float* __restrict__ p1b1,
        const float* __restrict__ p1w2, const float* __restrict__ p1b2,
        const float* __restrict__ p2w1, const float* __restrict__ p2b1,
        const float* __restrict__ p2w2, const float* __restrict__ p2b2,
        float* __restrict__ out) {
    __shared__ float wl[N_NODES];
    int t = threadIdx.x;
    const float4* w4 = (const float4*)wsq;
    float4* wl4 = (float4*)wl;
    for (int i = t; i < N_NODES / 4; i += 256) wl4[i] = w4[i];
    __syncthreads();

    int gw   = (int)((blockIdx.x * blockDim.x + t) >> 6);
    int lane = t & 63;
    int lid  = gw >> 14;
    int e    = gw & (EDGES - 1);
    int s = lid ? src1[e] : src0[e];
    int d = lid ? dst1[e] : dst0[e];
    const float4* rs = (const float4*)(A + (size_t)s * N_NODES);
    const float4* rd = (const float4*)(A + (size_t)d * N_NODES);
    float acc = 0.f;
#pragma unroll
    for (int i = 0; i < 16; ++i) {
        int idx = i * 64 + lane;
        float4 a = rs[idx];
        float4 b = rd[idx];
        float4 w = wl4[idx];
        acc = fmaf(a.x * b.x, w.x, acc);
        acc = fmaf(a.y * b.y, w.y, acc);
        acc = fmaf(a.z * b.z, w.z, acc);
        acc = fmaf(a.w * b.w, w.w, acc);
    }
    acc = wave_sum(acc);
    float x = acc / (dnorm[s] * dnorm[d]);
    mlp_epilogue(x, lid, e, lane, p1w1, p1b1, p1w2, p1b2, p2w1, p2b1, p2w2, p2b2, out);
}

extern "C" void kernel_launch(void* const* d_in, const int* in_sizes, int n_in,
                              void* d_out, int out_size, void* d_ws, size_t ws_size,
                              hipStream_t stream) {
    const float* A    = (const float*)d_in[0];
    const int*   src0 = (const int*)d_in[1];
    const int*   dst0 = (const int*)d_in[2];
    const int*   src1 = (const int*)d_in[3];
    const int*   dst1 = (const int*)d_in[4];
    const float* f0   = (const float*)d_in[5];
    const float* f1   = (const float*)d_in[6];
    const float* p1w1 = (const float*)d_in[7];
    const float* p1b1 = (const float*)d_in[8];
    const float* p1w2 = (const float*)d_in[9];
    const float* p1b2 = (const float*)d_in[10];
    const float* p2w1 = (const float*)d_in[11];
    const float* p2b1 = (const float*)d_in[12];
    const float* p2w2 = (const float*)d_in[13];
    const float* p2b2 = (const float*)d_in[14];
    float* out = (float*)d_out;

    float* ws  = (float*)d_ws;
    float* fm  = ws;
    float* wsq = ws + N_NODES;
    float* dn  = ws + 2 * N_NODES;
    float* P   = ws + 3 * N_NODES;                         // 8*32768 floats = 1 MB
    unsigned short* Bnew = (unsigned short*)(P + NCHUNK * 2 * EDGES);
    unsigned short* Bold = (unsigned short*)(ws + 3 * N_NODES);

    size_t need_new = (3ull * N_NODES + (size_t)NCHUNK * 2 * EDGES) * 4
                      + (size_t)N_NODES * N_NODES * 2;
    size_t need_old = 3ull * N_NODES * 4 + (size_t)N_NODES * N_NODES * 2;

    k_prep<<<N_NODES / 256, 256, 0, stream>>>(f0, f1, fm, wsq);
    if (ws_size >= need_new) {
        k_rows_fast<<<N_NODES, 256, 0, stream>>>(A, fm, Bnew, dn);
        k_edges_chunk<<<(2 * EDGES * NCHUNK) / 16, 256, 0, stream>>>(
            Bnew, src0, dst0, src1, dst1, P);
        k_finish<<<(2 * EDGES * 64) / 256, 256, 0, stream>>>(
            P, dn, src0, dst0, src1, dst1,
            p1w1, p1b1, p1w2, p1b2, p2w1, p2b1, p2w2, p2b2, out);
    } else if (ws_size >= need_old) {
        k_rows_fast<<<N_NODES, 256, 0, stream>>>(A, fm, Bold, dn);
        k_edges_fast<<<(2 * EDGES * 64) / 256, 256, 0, stream>>>(
            Bold, dn, src0, dst0, src1, dst1,
            p1w1, p1b1, p1w2, p1b2, p2w1, p2b1, p2w2, p2b2, out);
    } else {
        k_rows_slow<<<N_NODES, 256, 0, stream>>>(A, fm, dn);
        k_edges_slow<<<(2 * EDGES * 64) / 256, 256, 0, stream>>>(
            A, wsq, dn, src0, dst0, src1, dst1,
            p1w1, p1b1, p1w2, p1b2, p2w1, p2b1, p2w2, p2b2, out);
    }
}

// Round 4
// 160.041 us; speedup vs baseline: 1.1970x; 1.0805x over previous
//
#include <hip/hip_runtime.h>

#define N_NODES 4096
#define EDGES   16384
#define PHI     64
#define EPS_F   1e-8f
#define BETA_F  0.5f
#define NCHUNK  8
#define WCHUNK  512   // 512 bf16 cols = 1 KB rows per chunk; slab = 4 MB = one XCD L2

__device__ __forceinline__ float wave_sum(float v) {
#pragma unroll
    for (int off = 32; off > 0; off >>= 1) v += __shfl_xor(v, off, 64);
    return v;
}

__device__ __forceinline__ unsigned int pack_bf16(float f) {
    unsigned int u = __float_as_uint(f);
    u += 0x7fffu + ((u >> 16) & 1u);   // round-to-nearest-even
    return u >> 16;
}

// k0 (fallback paths only): f_mean, f_mean^2
__global__ void k_prep(const float* __restrict__ f0, const float* __restrict__ f1,
                       float* __restrict__ fm, float* __restrict__ wsq) {
    int i = blockIdx.x * blockDim.x + threadIdx.x;
    if (i < N_NODES) {
        float m = 0.5f * (f0[i] + f1[i]);
        fm[i]  = m;
        wsq[i] = m * m;
    }
}

// k1: per row v: B[v,:] = bf16(A[v,:]*fm), dnorm[v] = ||A[v,:]*fm + eps||
// fm computed inline from f0/f1 (16 KB each, L1-resident after first block).
__global__ void __launch_bounds__(256) k_rows_fast(const float* __restrict__ A,
                                                   const float* __restrict__ f0,
                                                   const float* __restrict__ f1,
                                                   unsigned short* __restrict__ B,
                                                   float* __restrict__ dnorm) {
    int row = blockIdx.x;
    const float4* a4  = (const float4*)(A + (size_t)row * N_NODES);
    const float4* f04 = (const float4*)f0;
    const float4* f14 = (const float4*)f1;
    uint2* b2 = (uint2*)(B + (size_t)row * N_NODES);
    int t = threadIdx.x;
    float acc = 0.f;
#pragma unroll
    for (int i = 0; i < 4; ++i) {
        int idx = i * 256 + t;
        float4 a = a4[idx];
        float4 fa = f04[idx];
        float4 fb = f14[idx];
        float fx = 0.5f * (fa.x + fb.x), fy = 0.5f * (fa.y + fb.y);
        float fz = 0.5f * (fa.z + fb.z), fw = 0.5f * (fa.w + fb.w);
        float b0 = a.x * fx, b1 = a.y * fy, b2v = a.z * fz, b3 = a.w * fw;
        float e0 = b0 + EPS_F, e1 = b1 + EPS_F, e2 = b2v + EPS_F, e3 = b3 + EPS_F;
        acc += e0 * e0 + e1 * e1 + e2 * e2 + e3 * e3;
        uint2 p;
        p.x = (pack_bf16(b1) << 16) | pack_bf16(b0);
        p.y = (pack_bf16(b3) << 16) | pack_bf16(b2v);
        b2[idx] = p;
    }
    acc = wave_sum(acc);
    __shared__ float red[4];
    if ((t & 63) == 0) red[t >> 6] = acc;
    __syncthreads();
    if (t == 0) dnorm[row] = sqrtf(red[0] + red[1] + red[2] + red[3]);
}

// k1 slow: dnorm only
__global__ void __launch_bounds__(256) k_rows_slow(const float* __restrict__ A,
                                                   const float* __restrict__ fm,
                                                   float* __restrict__ dnorm) {
    int row = blockIdx.x;
    const float4* a4  = (const float4*)(A + (size_t)row * N_NODES);
    const float4* fm4 = (const float4*)fm;
    int t = threadIdx.x;
    float acc = 0.f;
#pragma unroll
    for (int i = 0; i < 4; ++i) {
        int idx = i * 256 + t;
        float4 a = a4[idx];
        float4 f = fm4[idx];
        float e0 = a.x * f.x + EPS_F, e1 = a.y * f.y + EPS_F;
        float e2 = a.z * f.z + EPS_F, e3 = a.w * f.w + EPS_F;
        acc += e0 * e0 + e1 * e1 + e2 * e2 + e3 * e3;
    }
    acc = wave_sum(acc);
    __shared__ float red[4];
    if ((t & 63) == 0) red[t >> 6] = acc;
    __syncthreads();
    if (t == 0) dnorm[row] = sqrtf(red[0] + red[1] + red[2] + red[3]);
}

// Shared epilogue: given x = out_n, run both MLPs wave-parallel (lane = hidden idx)
__device__ __forceinline__ void mlp_epilogue(float x, int lid, int e, int lane,
                                             const float* __restrict__ p1w1, const float* __restrict__ p1b1,
                                             const float* __restrict__ p1w2, const float* __restrict__ p1b2,
                                             const float* __restrict__ p2w1, const float* __restrict__ p2b1,
                                             const float* __restrict__ p2w2, const float* __restrict__ p2b2,
                                             float* __restrict__ out) {
    int wi = lid * PHI + lane;
    float h1 = fmaxf(fmaf(x, p1w1[wi], p1b1[wi]), 0.f);
    float y1 = wave_sum(h1 * p1w2[wi]) + p1b2[lid];
    float sl1 = BETA_F * y1;   // LM = 1.0
    float h2 = fmaxf(fmaf(sl1, p2w1[wi], p2b1[wi]), 0.f);
    float y2 = wave_sum(h2 * p2w2[wi]) + p2b2[lid];
    if (lane == 0) out[lid * EDGES + e] = y2;
}

// k2: chunk = blockIdx & 7 -> one 4MB column-slab per XCD (L2-resident).
// 8 lanes per edge, 8 edges per wave (lane-parallel reduce, 3 shfl steps).
__global__ void __launch_bounds__(256) k_edges_chunk(
        const unsigned short* __restrict__ B,
        const int* __restrict__ src0, const int* __restrict__ dst0,
        const int* __restrict__ src1, const int* __restrict__ dst1,
        float* __restrict__ P) {
    int blk   = blockIdx.x;
    int chunk = blk & (NCHUNK - 1);
    int slot  = blk >> 3;                      // [0, 1024)
    int wave  = threadIdx.x >> 6;
    int lane  = threadIdx.x & 63;
    int g     = lane >> 3;                     // edge group within wave [0,8)
    int sub   = lane & 7;                      // lane within group

    int ge  = slot * 32 + wave * 8 + g;        // [0, 32768); 8-aligned per wave
    int lid = ge >> 14;
    int e   = ge & (EDGES - 1);
    int s = lid ? src1[e] : src0[e];
    int d = lid ? dst1[e] : dst0[e];

    const uint4* rs = (const uint4*)(B + (size_t)s * N_NODES + chunk * WCHUNK);
    const uint4* rd = (const uint4*)(B + (size_t)d * N_NODES + chunk * WCHUNK);

    uint4 us[8], ud[8];
#pragma unroll
    for (int i = 0; i < 8; ++i) {
        us[i] = rs[i * 8 + sub];
        ud[i] = rd[i * 8 + sub];
    }
    float acc = 0.f;
#pragma unroll
    for (int i = 0; i < 8; ++i) {
#define ACC_U(U, V)                                                    \
        {                                                              \
            float sl = __uint_as_float((U) << 16);                     \
            float sh = __uint_as_float((U) & 0xffff0000u);             \
            float dl = __uint_as_float((V) << 16);                     \
            float dh = __uint_as_float((V) & 0xffff0000u);             \
            acc = fmaf(sl, dl, acc);                                   \
            acc = fmaf(sh, dh, acc);                                   \
        }
        ACC_U(us[i].x, ud[i].x); ACC_U(us[i].y, ud[i].y);
        ACC_U(us[i].z, ud[i].z); ACC_U(us[i].w, ud[i].w);
#undef ACC_U
    }
    // 8-lane group reduce (3 steps, shared across all 8 edges of the wave)
    acc += __shfl_xor(acc, 1, 64);
    acc += __shfl_xor(acc, 2, 64);
    acc += __shfl_xor(acc, 4, 64);
    if (sub == 0) P[(size_t)chunk * (2 * EDGES) + ge] = acc;   // contiguous per wave
}

// k3: reduce 8 partials per edge, normalize, run both MLPs
__global__ void __launch_bounds__(256) k_finish(
        const float* __restrict__ P, const float* __restrict__ dnorm,
        const int* __restrict__ src0, const int* __restrict__ dst0,
        const int* __restrict__ src1, const int* __restrict__ dst1,
        const float* __restrict__ p1w1, const float* __restrict__ p1b1,
        const float* __restrict__ p1w2, const float* __restrict__ p1b2,
        const float* __restrict__ p2w1, const float* __restrict__ p2b1,
        const float* __restrict__ p2w2, const float* __restrict__ p2b2,
        float* __restrict__ out) {
    int gw   = (int)((blockIdx.x * blockDim.x + threadIdx.x) >> 6);   // [0, 32768)
    int lane = threadIdx.x & 63;
    int lid  = gw >> 14;
    int e    = gw & (EDGES - 1);
    int s = lid ? src1[e] : src0[e];
    int d = lid ? dst1[e] : dst0[e];
    float acc = 0.f;
#pragma unroll
    for (int c = 0; c < NCHUNK; ++c) acc += P[(size_t)c * (2 * EDGES) + gw];
    float x = acc / (dnorm[s] * dnorm[d]);
    mlp_epilogue(x, lid, e, lane, p1w1, p1b1, p1w2, p1b2, p2w1, p2b1, p2w2, p2b2, out);
}

// Round-2 fallback: one wave per edge over full rows (monolithic)
__global__ void __launch_bounds__(256) k_edges_fast(
        const unsigned short* __restrict__ B, const float* __restrict__ dnorm,
        const int* __restrict__ src0, const int* __restrict__ dst0,
        const int* __restrict__ src1, const int* __restrict__ dst1,
        const float* __restrict__ p1w1, const float* __restrict__ p1b1,
        const float* __restrict__ p1w2, const float* __restrict__ p1b2,
        const float* __restrict__ p2w1, const float* __restrict__ p2b1,
        const float* __restrict__ p2w2, const float* __restrict__ p2b2,
        float* __restrict__ out) {
    int gw   = (int)((blockIdx.x * blockDim.x + threadIdx.x) >> 6);
    int lane = threadIdx.x & 63;
    int lid  = gw >> 14;
    int e    = gw & (EDGES - 1);
    int s = lid ? src1[e] : src0[e];
    int d = lid ? dst1[e] : dst0[e];
    const uint4* rs = (const uint4*)(B + (size_t)s * N_NODES);
    const uint4* rd = (const uint4*)(B + (size_t)d * N_NODES);
    float acc = 0.f;
#pragma unroll
    for (int i = 0; i < 8; ++i) {
        uint4 us = rs[i * 64 + lane];
        uint4 ud = rd[i * 64 + lane];
#define ACC_U(U, V)                                                    \
        {                                                              \
            float sl = __uint_as_float((U) << 16);                     \
            float sh = __uint_as_float((U) & 0xffff0000u);             \
            float dl = __uint_as_float((V) << 16);                     \
            float dh = __uint_as_float((V) & 0xffff0000u);             \
            acc = fmaf(sl, dl, acc);                                   \
            acc = fmaf(sh, dh, acc);                                   \
        }
        ACC_U(us.x, ud.x); ACC_U(us.y, ud.y); ACC_U(us.z, ud.z); ACC_U(us.w, ud.w);
#undef ACC_U
    }
    acc = wave_sum(acc);
    float x = acc / (dnorm[s] * dnorm[d]);
    mlp_epilogue(x, lid, e, lane, p1w1, p1b1, p1w2, p1b2, p2w1, p2b1, p2w2, p2b2, out);
}

// Slow fallback: fp32 rows of A, weight w = fm^2 staged in LDS
__global__ void __launch_bounds__(256) k_edges_slow(
        const float* __restrict__ A, const float* __restrict__ wsq,
        const float* __restrict__ dnorm,
        const int* __restrict__ src0, const int* __restrict__ dst0,
        const int* __restrict__ src1, const int* __restrict__ dst1,
        const float* __restrict__ p1w1, const float* __restrict__ p1b1,
        const float* __restrict__ p1w2, const float* __restrict__ p1b2,
        const float* __restrict__ p2w1, const float* __restrict__ p2b1,
        const float* __restrict__ p2w2, const float* __restrict__ p2b2,
        float* __restrict__ out) {
    __shared__ float wl[N_NODES];
    int t = threadIdx.x;
    const float4* w4 = (const float4*)wsq;
    float4* wl4 = (float4*)wl;
    for (int i = t; i < N_NODES / 4; i += 256) wl4[i] = w4[i];
    __syncthreads();

    int gw   = (int)((blockIdx.x * blockDim.x + t) >> 6);
    int lane = t & 63;
    int lid  = gw >> 14;
    int e    = gw & (EDGES - 1);
    int s = lid ? src1[e] : src0[e];
    int d = lid ? dst1[e] : dst0[e];
    const float4* rs = (const float4*)(A + (size_t)s * N_NODES);
    const float4* rd = (const float4*)(A + (size_t)d * N_NODES);
    float acc = 0.f;
#pragma unroll
    for (int i = 0; i < 16; ++i) {
        int idx = i * 64 + lane;
        float4 a = rs[idx];
        float4 b = rd[idx];
        float4 w = wl4[idx];
        acc = fmaf(a.x * b.x, w.x, acc);
        acc = fmaf(a.y * b.y, w.y, acc);
        acc = fmaf(a.z * b.z, w.z, acc);
        acc = fmaf(a.w * b.w, w.w, acc);
    }
    acc = wave_sum(acc);
    float x = acc / (dnorm[s] * dnorm[d]);
    mlp_epilogue(x, lid, e, lane, p1w1, p1b1, p1w2, p1b2, p2w1, p2b1, p2w2, p2b2, out);
}

extern "C" void kernel_launch(void* const* d_in, const int* in_sizes, int n_in,
                              void* d_out, int out_size, void* d_ws, size_t ws_size,
                              hipStream_t stream) {
    const float* A    = (const float*)d_in[0];
    const int*   src0 = (const int*)d_in[1];
    const int*   dst0 = (const int*)d_in[2];
    const int*   src1 = (const int*)d_in[3];
    const int*   dst1 = (const int*)d_in[4];
    const float* f0   = (const float*)d_in[5];
    const float* f1   = (const float*)d_in[6];
    const float* p1w1 = (const float*)d_in[7];
    const float* p1b1 = (const float*)d_in[8];
    const float* p1w2 = (const float*)d_in[9];
    const float* p1b2 = (const float*)d_in[10];
    const float* p2w1 = (const float*)d_in[11];
    const float* p2b1 = (const float*)d_in[12];
    const float* p2w2 = (const float*)d_in[13];
    const float* p2b2 = (const float*)d_in[14];
    float* out = (float*)d_out;

    float* ws  = (float*)d_ws;
    float* fm  = ws;
    float* wsq = ws + N_NODES;
    float* dn  = ws + 2 * N_NODES;
    float* P   = ws + 3 * N_NODES;                         // 8*32768 floats = 1 MB
    unsigned short* Bnew = (unsigned short*)(P + NCHUNK * 2 * EDGES);
    unsigned short* Bold = (unsigned short*)(ws + 3 * N_NODES);

    size_t need_new = (3ull * N_NODES + (size_t)NCHUNK * 2 * EDGES) * 4
                      + (size_t)N_NODES * N_NODES * 2;
    size_t need_old = 3ull * N_NODES * 4 + (size_t)N_NODES * N_NODES * 2;

    if (ws_size >= need_new) {
        k_rows_fast<<<N_NODES, 256, 0, stream>>>(A, f0, f1, Bnew, dn);
        k_edges_chunk<<<(2 * EDGES * NCHUNK) / 32, 256, 0, stream>>>(
            Bnew, src0, dst0, src1, dst1, P);
        k_finish<<<(2 * EDGES * 64) / 256, 256, 0, stream>>>(
            P, dn, src0, dst0, src1, dst1,
            p1w1, p1b1, p1w2, p1b2, p2w1, p2b1, p2w2, p2b2, out);
    } else if (ws_size >= need_old) {
        k_prep<<<N_NODES / 256, 256, 0, stream>>>(f0, f1, fm, wsq);
        k_rows_fast<<<N_NODES, 256, 0, stream>>>(A, f0, f1, Bold, dn);
        k_edges_fast<<<(2 * EDGES * 64) / 256, 256, 0, stream>>>(
            Bold, dn, src0, dst0, src1, dst1,
            p1w1, p1b1, p1w2, p1b2, p2w1, p2b1, p2w2, p2b2, out);
    } else {
        k_prep<<<N_NODES / 256, 256, 0, stream>>>(f0, f1, fm, wsq);
        k_rows_slow<<<N_NODES, 256, 0, stream>>>(A, fm, dn);
        k_edges_slow<<<(2 * EDGES * 64) / 256, 256, 0, stream>>>(
            A, wsq, dn, src0, dst0, src1, dst1,
            p1w1, p1b1, p1w2, p1b2, p2w1, p2b1, p2w2, p2b2, out);
    }
}

// Round 5
// 156.712 us; speedup vs baseline: 1.2224x; 1.0212x over previous
//
#include <hip/hip_runtime.h>

#define N_NODES 4096
#define EDGES   16384
#define PHI     64
#define EPS_F   1e-8f
#define BETA_F  0.5f
#define NCHUNK  8
#define WCHUNK  512   // 512 bf16 cols = 1 KB per row-chunk; slab = 4 MB = one XCD L2

__device__ __forceinline__ float wave_sum(float v) {
#pragma unroll
    for (int off = 32; off > 0; off >>= 1) v += __shfl_xor(v, off, 64);
    return v;
}

__device__ __forceinline__ unsigned int pack_bf16(float f) {
    unsigned int u = __float_as_uint(f);
    u += 0x7fffu + ((u >> 16) & 1u);   // round-to-nearest-even
    return u >> 16;
}

// k0 (fallback paths only): f_mean, f_mean^2
__global__ void k_prep(const float* __restrict__ f0, const float* __restrict__ f1,
                       float* __restrict__ fm, float* __restrict__ wsq) {
    int i = blockIdx.x * blockDim.x + threadIdx.x;
    if (i < N_NODES) {
        float m = 0.5f * (f0[i] + f1[i]);
        fm[i]  = m;
        wsq[i] = m * m;
    }
}

// k1: per row v: B[v,:] = bf16(A[v,:]*fm), dnorm[v] = ||A[v,:]*fm + eps||
// fm computed inline from f0/f1 (16 KB each, L1/L2-resident after first blocks).
__global__ void __launch_bounds__(256) k_rows_fast(const float* __restrict__ A,
                                                   const float* __restrict__ f0,
                                                   const float* __restrict__ f1,
                                                   unsigned short* __restrict__ B,
                                                   float* __restrict__ dnorm) {
    int row = blockIdx.x;
    const float4* a4  = (const float4*)(A + (size_t)row * N_NODES);
    const float4* f04 = (const float4*)f0;
    const float4* f14 = (const float4*)f1;
    uint2* b2 = (uint2*)(B + (size_t)row * N_NODES);
    int t = threadIdx.x;
    float acc = 0.f;
#pragma unroll
    for (int i = 0; i < 4; ++i) {
        int idx = i * 256 + t;
        float4 a = a4[idx];
        float4 fa = f04[idx];
        float4 fb = f14[idx];
        float fx = 0.5f * (fa.x + fb.x), fy = 0.5f * (fa.y + fb.y);
        float fz = 0.5f * (fa.z + fb.z), fw = 0.5f * (fa.w + fb.w);
        float b0 = a.x * fx, b1 = a.y * fy, b2v = a.z * fz, b3 = a.w * fw;
        float e0 = b0 + EPS_F, e1 = b1 + EPS_F, e2 = b2v + EPS_F, e3 = b3 + EPS_F;
        acc += e0 * e0 + e1 * e1 + e2 * e2 + e3 * e3;
        uint2 p;
        p.x = (pack_bf16(b1) << 16) | pack_bf16(b0);
        p.y = (pack_bf16(b3) << 16) | pack_bf16(b2v);
        b2[idx] = p;
    }
    acc = wave_sum(acc);
    __shared__ float red[4];
    if ((t & 63) == 0) red[t >> 6] = acc;
    __syncthreads();
    if (t == 0) dnorm[row] = sqrtf(red[0] + red[1] + red[2] + red[3]);
}

// k1 slow: dnorm only
__global__ void __launch_bounds__(256) k_rows_slow(const float* __restrict__ A,
                                                   const float* __restrict__ fm,
                                                   float* __restrict__ dnorm) {
    int row = blockIdx.x;
    const float4* a4  = (const float4*)(A + (size_t)row * N_NODES);
    const float4* fm4 = (const float4*)fm;
    int t = threadIdx.x;
    float acc = 0.f;
#pragma unroll
    for (int i = 0; i < 4; ++i) {
        int idx = i * 256 + t;
        float4 a = a4[idx];
        float4 f = fm4[idx];
        float e0 = a.x * f.x + EPS_F, e1 = a.y * f.y + EPS_F;
        float e2 = a.z * f.z + EPS_F, e3 = a.w * f.w + EPS_F;
        acc += e0 * e0 + e1 * e1 + e2 * e2 + e3 * e3;
    }
    acc = wave_sum(acc);
    __shared__ float red[4];
    if ((t & 63) == 0) red[t >> 6] = acc;
    __syncthreads();
    if (t == 0) dnorm[row] = sqrtf(red[0] + red[1] + red[2] + red[3]);
}

// Shared epilogue: given x = out_n, run both MLPs wave-parallel (lane = hidden idx)
__device__ __forceinline__ void mlp_epilogue(float x, int lid, int e, int lane,
                                             const float* __restrict__ p1w1, const float* __restrict__ p1b1,
                                             const float* __restrict__ p1w2, const float* __restrict__ p1b2,
                                             const float* __restrict__ p2w1, const float* __restrict__ p2b1,
                                             const float* __restrict__ p2w2, const float* __restrict__ p2b2,
                                             float* __restrict__ out) {
    int wi = lid * PHI + lane;
    float h1 = fmaxf(fmaf(x, p1w1[wi], p1b1[wi]), 0.f);
    float y1 = wave_sum(h1 * p1w2[wi]) + p1b2[lid];
    float sl1 = BETA_F * y1;   // LM = 1.0
    float h2 = fmaxf(fmaf(sl1, p2w1[wi], p2b1[wi]), 0.f);
    float y2 = wave_sum(h2 * p2w2[wi]) + p2b2[lid];
    if (lane == 0) out[lid * EDGES + e] = y2;
}

// k2: chunk = blockIdx & 7 -> one 4MB column-slab per XCD (L2-resident).
// 8 lanes per edge, 8 edges per wave. Two 4-uint4 passes keep live staging at
// 32 VGPR; __launch_bounds__(256,8) caps VGPR<=64 -> 8 waves/SIMD for L2
// latency hiding.
__global__ void __launch_bounds__(256, 8) k_edges_chunk(
        const unsigned short* __restrict__ B,
        const int* __restrict__ src0, const int* __restrict__ dst0,
        const int* __restrict__ src1, const int* __restrict__ dst1,
        float* __restrict__ P) {
    int blk   = blockIdx.x;
    int chunk = blk & (NCHUNK - 1);
    int slot  = blk >> 3;                      // [0, 1024)
    int wave  = threadIdx.x >> 6;
    int lane  = threadIdx.x & 63;
    int g     = lane >> 3;                     // edge group within wave [0,8)
    int sub   = lane & 7;                      // lane within group

    int ge  = slot * 32 + wave * 8 + g;        // [0, 32768); 8-aligned per wave
    int lid = ge >> 14;
    int e   = ge & (EDGES - 1);
    int s = lid ? src1[e] : src0[e];
    int d = lid ? dst1[e] : dst0[e];

    const uint4* rs = (const uint4*)(B + (size_t)s * N_NODES + chunk * WCHUNK) + sub;
    const uint4* rd = (const uint4*)(B + (size_t)d * N_NODES + chunk * WCHUNK) + sub;

    float acc = 0.f;
#pragma unroll
    for (int h = 0; h < 2; ++h) {
        uint4 us[4], ud[4];
#pragma unroll
        for (int i = 0; i < 4; ++i) {
            us[i] = rs[(h * 4 + i) * 8];
            ud[i] = rd[(h * 4 + i) * 8];
        }
#pragma unroll
        for (int i = 0; i < 4; ++i) {
#define ACC_U(U, V)                                                    \
            {                                                          \
                float sl = __uint_as_float((U) << 16);                 \
                float sh = __uint_as_float((U) & 0xffff0000u);         \
                float dl = __uint_as_float((V) << 16);                 \
                float dh = __uint_as_float((V) & 0xffff0000u);         \
                acc = fmaf(sl, dl, acc);                               \
                acc = fmaf(sh, dh, acc);                               \
            }
            ACC_U(us[i].x, ud[i].x); ACC_U(us[i].y, ud[i].y);
            ACC_U(us[i].z, ud[i].z); ACC_U(us[i].w, ud[i].w);
#undef ACC_U
        }
    }
    // 8-lane group reduce (3 steps, shared across all 8 edges of the wave)
    acc += __shfl_xor(acc, 1, 64);
    acc += __shfl_xor(acc, 2, 64);
    acc += __shfl_xor(acc, 4, 64);
    if (sub == 0) P[(size_t)chunk * (2 * EDGES) + ge] = acc;   // contiguous per wave
}

// k3: reduce 8 partials per edge, normalize, run both MLPs
__global__ void __launch_bounds__(256) k_finish(
        const float* __restrict__ P, const float* __restrict__ dnorm,
        const int* __restrict__ src0, const int* __restrict__ dst0,
        const int* __restrict__ src1, const int* __restrict__ dst1,
        const float* __restrict__ p1w1, const float* __restrict__ p1b1,
        const float* __restrict__ p1w2, const float* __restrict__ p1b2,
        const float* __restrict__ p2w1, const float* __restrict__ p2b1,
        const float* __restrict__ p2w2, const float* __restrict__ p2b2,
        float* __restrict__ out) {
    int gw   = (int)((blockIdx.x * blockDim.x + threadIdx.x) >> 6);   // [0, 32768)
    int lane = threadIdx.x & 63;
    int lid  = gw >> 14;
    int e    = gw & (EDGES - 1);
    int s = lid ? src1[e] : src0[e];
    int d = lid ? dst1[e] : dst0[e];
    float acc = 0.f;
#pragma unroll
    for (int c = 0; c < NCHUNK; ++c) acc += P[(size_t)c * (2 * EDGES) + gw];
    float x = acc / (dnorm[s] * dnorm[d]);
    mlp_epilogue(x, lid, e, lane, p1w1, p1b1, p1w2, p1b2, p2w1, p2b1, p2w2, p2b2, out);
}

// Round-2 fallback: one wave per edge over full rows (monolithic)
__global__ void __launch_bounds__(256) k_edges_fast(
        const unsigned short* __restrict__ B, const float* __restrict__ dnorm,
        const int* __restrict__ src0, const int* __restrict__ dst0,
        const int* __restrict__ src1, const int* __restrict__ dst1,
        const float* __restrict__ p1w1, const float* __restrict__ p1b1,
        const float* __restrict__ p1w2, const float* __restrict__ p1b2,
        const float* __restrict__ p2w1, const float* __restrict__ p2b1,
        const float* __restrict__ p2w2, const float* __restrict__ p2b2,
        float* __restrict__ out) {
    int gw   = (int)((blockIdx.x * blockDim.x + threadIdx.x) >> 6);
    int lane = threadIdx.x & 63;
    int lid  = gw >> 14;
    int e    = gw & (EDGES - 1);
    int s = lid ? src1[e] : src0[e];
    int d = lid ? dst1[e] : dst0[e];
    const uint4* rs = (const uint4*)(B + (size_t)s * N_NODES);
    const uint4* rd = (const uint4*)(B + (size_t)d * N_NODES);
    float acc = 0.f;
#pragma unroll
    for (int i = 0; i < 8; ++i) {
        uint4 us = rs[i * 64 + lane];
        uint4 ud = rd[i * 64 + lane];
#define ACC_U(U, V)                                                    \
        {                                                              \
            float sl = __uint_as_float((U) << 16);                     \
            float sh = __uint_as_float((U) & 0xffff0000u);             \
            float dl = __uint_as_float((V) << 16);                     \
            float dh = __uint_as_float((V) & 0xffff0000u);             \
            acc = fmaf(sl, dl, acc);                                   \
            acc = fmaf(sh, dh, acc);                                   \
        }
        ACC_U(us.x, ud.x); ACC_U(us.y, ud.y); ACC_U(us.z, ud.z); ACC_U(us.w, ud.w);
#undef ACC_U
    }
    acc = wave_sum(acc);
    float x = acc / (dnorm[s] * dnorm[d]);
    mlp_epilogue(x, lid, e, lane, p1w1, p1b1, p1w2, p1b2, p2w1, p2b1, p2w2, p2b2, out);
}

// Slow fallback: fp32 rows of A, weight w = fm^2 staged in LDS
__global__ void __launch_bounds__(256) k_edges_slow(
        const float* __restrict__ A, const float* __restrict__ wsq,
        const float* __restrict__ dnorm,
        const int* __restrict__ src0, const int* __restrict__ dst0,
        const int* __restrict__ src1, const int* __restrict__ dst1,
        const float* __restrict__ p1w1, const float* __restrict__ p1b1,
        const float* __restrict__ p1w2, const float* __restrict__ p1b2,
        const float* __restrict__ p2w1, const float* __restrict__ p2b1,
        const float* __restrict__ p2w2, const float* __restrict__ p2b2,
        float* __restrict__ out) {
    __shared__ float wl[N_NODES];
    int t = threadIdx.x;
    const float4* w4 = (const float4*)wsq;
    float4* wl4 = (float4*)wl;
    for (int i = t; i < N_NODES / 4; i += 256) wl4[i] = w4[i];
    __syncthreads();

    int gw   = (int)((blockIdx.x * blockDim.x + t) >> 6);
    int lane = t & 63;
    int lid  = gw >> 14;
    int e    = gw & (EDGES - 1);
    int s = lid ? src1[e] : src0[e];
    int d = lid ? dst1[e] : dst0[e];
    const float4* rs = (const float4*)(A + (size_t)s * N_NODES);
    const float4* rd = (const float4*)(A + (size_t)d * N_NODES);
    float acc = 0.f;
#pragma unroll
    for (int i = 0; i < 16; ++i) {
        int idx = i * 64 + lane;
        float4 a = rs[idx];
        float4 b = rd[idx];
        float4 w = wl4[idx];
        acc = fmaf(a.x * b.x, w.x, acc);
        acc = fmaf(a.y * b.y, w.y, acc);
        acc = fmaf(a.z * b.z, w.z, acc);
        acc = fmaf(a.w * b.w, w.w, acc);
    }
    acc = wave_sum(acc);
    float x = acc / (dnorm[s] * dnorm[d]);
    mlp_epilogue(x, lid, e, lane, p1w1, p1b1, p1w2, p1b2, p2w1, p2b1, p2w2, p2b2, out);
}

extern "C" void kernel_launch(void* const* d_in, const int* in_sizes, int n_in,
                              void* d_out, int out_size, void* d_ws, size_t ws_size,
                              hipStream_t stream) {
    const float* A    = (const float*)d_in[0];
    const int*   src0 = (const int*)d_in[1];
    const int*   dst0 = (const int*)d_in[2];
    const int*   src1 = (const int*)d_in[3];
    const int*   dst1 = (const int*)d_in[4];
    const float* f0   = (const float*)d_in[5];
    const float* f1   = (const float*)d_in[6];
    const float* p1w1 = (const float*)d_in[7];
    const float* p1b1 = (const float*)d_in[8];
    const float* p1w2 = (const float*)d_in[9];
    const float* p1b2 = (const float*)d_in[10];
    const float* p2w1 = (const float*)d_in[11];
    const float* p2b1 = (const float*)d_in[12];
    const float* p2w2 = (const float*)d_in[13];
    const float* p2b2 = (const float*)d_in[14];
    float* out = (float*)d_out;

    float* ws  = (float*)d_ws;
    float* fm  = ws;
    float* wsq = ws + N_NODES;
    float* dn  = ws + 2 * N_NODES;
    float* P   = ws + 3 * N_NODES;                         // 8*32768 floats = 1 MB
    unsigned short* Bnew = (unsigned short*)(P + NCHUNK * 2 * EDGES);
    unsigned short* Bold = (unsigned short*)(ws + 3 * N_NODES);

    size_t need_new = (3ull * N_NODES + (size_t)NCHUNK * 2 * EDGES) * 4
                      + (size_t)N_NODES * N_NODES * 2;
    size_t need_old = 3ull * N_NODES * 4 + (size_t)N_NODES * N_NODES * 2;

    if (ws_size >= need_new) {
        k_rows_fast<<<N_NODES, 256, 0, stream>>>(A, f0, f1, Bnew, dn);
        k_edges_chunk<<<(2 * EDGES * NCHUNK) / 32, 256, 0, stream>>>(
            Bnew, src0, dst0, src1, dst1, P);
        k_finish<<<(2 * EDGES * 64) / 256, 256, 0, stream>>>(
            P, dn, src0, dst0, src1, dst1,
            p1w1, p1b1, p1w2, p1b2, p2w1, p2b1, p2w2, p2b2, out);
    } else if (ws_size >= need_old) {
        k_prep<<<N_NODES / 256, 256, 0, stream>>>(f0, f1, fm, wsq);
        k_rows_fast<<<N_NODES, 256, 0, stream>>>(A, f0, f1, Bold, dn);
        k_edges_fast<<<(2 * EDGES * 64) / 256, 256, 0, stream>>>(
            Bold, dn, src0, dst0, src1, dst1,
            p1w1, p1b1, p1w2, p1b2, p2w1, p2b1, p2w2, p2b2, out);
    } else {
        k_prep<<<N_NODES / 256, 256, 0, stream>>>(f0, f1, fm, wsq);
        k_rows_slow<<<N_NODES, 256, 0, stream>>>(A, fm, dn);
        k_edges_slow<<<(2 * EDGES * 64) / 256, 256, 0, stream>>>(
            A, wsq, dn, src0, dst0, src1, dst1,
            p1w1, p1b1, p1w2, p1b2, p2w1, p2b1, p2w2, p2b2, out);
    }
}